// Round 4
// baseline (449.352 us; speedup 1.0000x reference)
//
#include <hip/hip_runtime.h>
#include <stdint.h>

#define N_NODES 10000
#define N_EDGES 160000
#define D 512
#define TOT (N_NODES * D)          // 5,120,000
#define NMASK (TOT / 32)           // 160,000 u32 words per dropout mask

typedef _Float16 h8 __attribute__((ext_vector_type(8)));
typedef float f4 __attribute__((ext_vector_type(4)));

// ---------------- threefry2x32 (JAX partitionable semantics) ----------------
__host__ __device__ inline uint32_t rotl32(uint32_t v, int r) {
    return (v << r) | (v >> (32 - r));
}

__host__ __device__ inline void tf2x32(uint32_t k0, uint32_t k1,
                                       uint32_t& x0, uint32_t& x1) {
    uint32_t k2 = k0 ^ k1 ^ 0x1BD11BDAu;
    x0 += k0; x1 += k1;
    x0 += x1; x1 = rotl32(x1, 13); x1 ^= x0;
    x0 += x1; x1 = rotl32(x1, 15); x1 ^= x0;
    x0 += x1; x1 = rotl32(x1, 26); x1 ^= x0;
    x0 += x1; x1 = rotl32(x1,  6); x1 ^= x0;
    x0 += k1; x1 += k2 + 1u;
    x0 += x1; x1 = rotl32(x1, 17); x1 ^= x0;
    x0 += x1; x1 = rotl32(x1, 29); x1 ^= x0;
    x0 += x1; x1 = rotl32(x1, 16); x1 ^= x0;
    x0 += x1; x1 = rotl32(x1, 24); x1 ^= x0;
    x0 += k2; x1 += k0 + 2u;
    x0 += x1; x1 = rotl32(x1, 13); x1 ^= x0;
    x0 += x1; x1 = rotl32(x1, 15); x1 ^= x0;
    x0 += x1; x1 = rotl32(x1, 26); x1 ^= x0;
    x0 += x1; x1 = rotl32(x1,  6); x1 ^= x0;
    x0 += k0; x1 += k1 + 3u;
    x0 += x1; x1 = rotl32(x1, 17); x1 ^= x0;
    x0 += x1; x1 = rotl32(x1, 29); x1 ^= x0;
    x0 += x1; x1 = rotl32(x1, 16); x1 ^= x0;
    x0 += x1; x1 = rotl32(x1, 24); x1 ^= x0;
    x0 += k1; x1 += k2 + 4u;
    x0 += x1; x1 = rotl32(x1, 13); x1 ^= x0;
    x0 += x1; x1 = rotl32(x1, 15); x1 ^= x0;
    x0 += x1; x1 = rotl32(x1, 26); x1 ^= x0;
    x0 += x1; x1 = rotl32(x1,  6); x1 ^= x0;
    x0 += k2; x1 += k0 + 5u;
}

__device__ __forceinline__ uint32_t dropout_bit(uint32_t k0, uint32_t k1, uint32_t j) {
    uint32_t c0 = 0u, c1 = j;
    tf2x32(k0, k1, c0, c1);
    uint32_t bits = c0 ^ c1;
    float u = __uint_as_float((bits >> 9) | 0x3f800000u) - 1.0f;
    return (u < 0.8f) ? 1u : 0u;
}

// ---------------- fused pre-pass: hist + Wt + dropout0 + mask1 + mask2 ------
// block ranges: [0,625) hist, [625,817) wconvert, [817,5817) dropout layer 0,
// [5817,6442) mask for layer-0 epilogue, [6442,7067) mask for layer-1 epilogue.
#define HIST_BLKS 625
#define WCONV_BLKS 192
#define DROP_BLKS 5000
#define MASKG_BLKS 625             // NMASK / 256
#define PRE_BLKS (HIST_BLKS + WCONV_BLKS + DROP_BLKS + 2 * MASKG_BLKS)
__global__ __launch_bounds__(256)
void pre_kernel(const int* __restrict__ src, const int* __restrict__ dst,
                int* __restrict__ deg_out, int* __restrict__ deg_in,
                const float* __restrict__ W0, const float* __restrict__ W1,
                const float* __restrict__ W2, _Float16* __restrict__ Wt,
                const float* __restrict__ x, _Float16* __restrict__ y,
                uint32_t k0, uint32_t k1,
                uint32_t m1k0, uint32_t m1k1, uint32_t* __restrict__ mask1,
                uint32_t m2k0, uint32_t m2k1, uint32_t* __restrict__ mask2) {
    __shared__ float tile[64][65];
    int b = blockIdx.x;
    int t = threadIdx.x;
    if (b < HIST_BLKS) {
        int e = b * 256 + t;
        if (e < N_EDGES) {
            atomicAdd(&deg_out[src[e]], 1);
            atomicAdd(&deg_in[dst[e]], 1);
        }
    } else if (b < HIST_BLKS + WCONV_BLKS) {
        int b2 = b - HIST_BLKS;
        int bx = b2 & 7, by = (b2 >> 3) & 7, bz = b2 >> 6;
        const float* W = (bz == 0) ? W0 : (bz == 1) ? W1 : W2;
        _Float16* T = Wt + (size_t)bz * 512 * 512;
        int r0 = by * 64, c0 = bx * 64;
        int c = t & 63, rq = t >> 6;
#pragma unroll
        for (int i = 0; i < 16; ++i) {
            int r = rq + i * 4;
            tile[r][c] = W[(size_t)(r0 + r) * 512 + c0 + c];
        }
        __syncthreads();
        int k = t & 63, nq = t >> 6;
#pragma unroll
        for (int i = 0; i < 16; ++i) {
            int n = nq + i * 4;
            T[(size_t)(c0 + n) * 512 + r0 + k] = (_Float16)tile[k][n];
        }
    } else if (b < HIST_BLKS + WCONV_BLKS + DROP_BLKS) {
        int b3 = b - HIST_BLKS - WCONV_BLKS;
        int j = (b3 * 256 + t) * 4;
        if (j >= TOT) return;
        float4 xv = *(const float4*)&x[j];
        _Float16 r[4];
        uint32_t jj = (uint32_t)j;
#pragma unroll
        for (int i = 0; i < 4; ++i) {
            float g = dropout_bit(k0, k1, jj + (uint32_t)i) ? 1.0f : 0.0f;
            float xi = (&xv.x)[i];
            r[i] = (_Float16)(g * (xi * 1.25f));
        }
        *(ushort4*)&y[j] = *(ushort4*)r;
    } else {
        int b4 = b - HIST_BLKS - WCONV_BLKS - DROP_BLKS;
        int which = b4 / MASKG_BLKS;               // 0 -> mask1, 1 -> mask2
        int gtid = (b4 % MASKG_BLKS) * 256 + t;    // 0..159999
        uint32_t mk0 = which ? m2k0 : m1k0;
        uint32_t mk1 = which ? m2k1 : m1k1;
        uint32_t* m = which ? mask2 : mask1;
        uint32_t w = 0, jb = (uint32_t)gtid * 32u;
#pragma unroll 4
        for (int i = 0; i < 32; ++i)
            w |= dropout_bit(mk0, mk1, jb + (uint32_t)i) << i;
        m[gtid] = w;
    }
}

// ---------------- single-pass scan: 1024 threads x 10 elems, 2 barriers -----
__global__ __launch_bounds__(1024)
void scan_kernel(const int* __restrict__ deg_in, const int* __restrict__ deg_out,
                 int* __restrict__ row_ptr,
                 float* __restrict__ rn_in, float* __restrict__ rn_out) {
    __shared__ int wsum[16];
    int tid = threadIdx.x;
    int lane = tid & 63, wv = tid >> 6;
    int base = tid * 10;
    int v[10];
    int tot = 0;
#pragma unroll
    for (int i = 0; i < 10; ++i) {
        int idx = base + i;
        v[i] = (idx < N_NODES) ? deg_in[idx] : 0;
        tot += v[i];
    }
    int s = tot;
#pragma unroll
    for (int off = 1; off < 64; off <<= 1) {
        int t = __shfl_up(s, off, 64);
        if (lane >= off) s += t;
    }
    if (lane == 63) wsum[wv] = s;
    __syncthreads();
    if (wv == 0 && lane < 16) {
        int ws = wsum[lane];
#pragma unroll
        for (int off = 1; off < 16; off <<= 1) {
            int t = __shfl_up(ws, off, 64);
            if (lane >= off) ws += t;
        }
        wsum[lane] = ws;
    }
    __syncthreads();
    int run = ((wv > 0) ? wsum[wv - 1] : 0) + (s - tot);
#pragma unroll
    for (int i = 0; i < 10; ++i) {
        int idx = base + i;
        if (idx < N_NODES) {
            row_ptr[idx] = run;
            rn_in[idx]  = 1.0f / sqrtf(fmaxf((float)v[i], 1.0f));
            rn_out[idx] = 1.0f / sqrtf(fmaxf((float)deg_out[idx], 1.0f));
        }
        run += v[i];
    }
    if (tid == 1023) row_ptr[N_NODES] = wsum[15];
}

// ---------------- CSR fill; edge weight pre-multiplied by rn_out[src] -------
__global__ void fill_kernel(const int* __restrict__ src, const int* __restrict__ dst,
                            const float* __restrict__ ew, const int* __restrict__ row_ptr,
                            const float* __restrict__ rn_out,
                            int* __restrict__ cursor, int2* __restrict__ csr) {
    int e = blockIdx.x * 256 + threadIdx.x;
    if (e >= N_EDGES) return;
    int v = dst[e];
    int sn = src[e];
    int pos = atomicAdd(&cursor[v], 1);
    int idx = row_ptr[v] + pos;
    csr[idx] = make_int2(sn, __float_as_int(ew[e] * rn_out[sn]));
}

// ---------------- fused aggregate + GEMM + epilogue, one layer --------------
// 625 single-wave blocks; block b owns the 16-row m-tile [b*16, b*16+16).
// Phase 1: gather the 16 agg rows (full K=512) into a 16x520 LDS slab
//          (16-deep edge unroll -> 16 outstanding 1KB gathers per wave).
// Phase 2: A-fragments (16 x h8 = 64 VGPR) loaded from LDS once; B streamed
//          from global (L2-resident 512KB, reused by all 625 waves) into
//          double-buffered register fragments; per 16x16 n-tile: 16 MFMA in
//          4 independent chains (dep-latency hidden), immediate epilogue.
// Phase 3 (mode 0): ELU + mask-bit dropout + rn_in, restage through LDS,
//          16 coalesced 1KB row stores. mode 1: direct f32 stores.
// No barriers beyond intra-wave LDS ordering (block == 1 wave).
#define LDF 520                    // 1040 B row stride: banks shift 4/row
__global__ __launch_bounds__(64)
void fused_kernel(const _Float16* __restrict__ yin, const int* __restrict__ row_ptr,
                  const int2* __restrict__ csr, const _Float16* __restrict__ Wt,
                  const float* __restrict__ bias, const float* __restrict__ rn_in,
                  const uint32_t* __restrict__ mask,
                  _Float16* __restrict__ yout, float* __restrict__ fout, int mode) {
    __shared__ _Float16 AT[16 * LDF];   // 16.6 KB
    const int lane = threadIdx.x;
    const int base = blockIdx.x * 16;
    const _Float16* yl = yin + lane * 8;

    // ---- phase 1: gather ----
    for (int i = 0; i < 16; ++i) {
        int beg = row_ptr[base + i], end = row_ptr[base + i + 1];
        float acc[8] = {0, 0, 0, 0, 0, 0, 0, 0};
        int k = beg;
        for (; k + 15 < end; k += 16) {
            int2 e[16];
#pragma unroll
            for (int u = 0; u < 16; ++u) e[u] = csr[k + u];
            h8 v[16];
#pragma unroll
            for (int u = 0; u < 16; ++u) v[u] = *(const h8*)&yl[(size_t)e[u].x * 512];
#pragma unroll
            for (int u = 0; u < 16; ++u) {
                float w = __int_as_float(e[u].y);
#pragma unroll
                for (int j = 0; j < 8; ++j) acc[j] += w * (float)v[u][j];
            }
        }
        for (; k + 3 < end; k += 4) {
            int2 e[4];
#pragma unroll
            for (int u = 0; u < 4; ++u) e[u] = csr[k + u];
            h8 v[4];
#pragma unroll
            for (int u = 0; u < 4; ++u) v[u] = *(const h8*)&yl[(size_t)e[u].x * 512];
#pragma unroll
            for (int u = 0; u < 4; ++u) {
                float w = __int_as_float(e[u].y);
#pragma unroll
                for (int j = 0; j < 8; ++j) acc[j] += w * (float)v[u][j];
            }
        }
        for (; k < end; ++k) {
            int2 e0 = csr[k];
            float w = __int_as_float(e0.y);
            h8 v = *(const h8*)&yl[(size_t)e0.x * 512];
#pragma unroll
            for (int j = 0; j < 8; ++j) acc[j] += w * (float)v[j];
        }
        _Float16 r[8];
#pragma unroll
        for (int j = 0; j < 8; ++j) r[j] = (_Float16)acc[j];
        *(h8*)&AT[i * LDF + lane * 8] = *(h8*)r;
    }
    __syncthreads();                     // intra-wave LDS write->read ordering

    // ---- phase 2: A-frags to registers, then stream B ----
    h8 a[16];
#pragma unroll
    for (int ks = 0; ks < 16; ++ks)
        a[ks] = *(const h8*)&AT[(lane & 15) * LDF + ks * 32 + (lane >> 4) * 8];
    __syncthreads();                     // AT now reusable as output staging

    const int r0 = (lane >> 4) * 4;
    float rn[4];
#pragma unroll
    for (int i = 0; i < 4; ++i) rn[i] = rn_in[base + r0 + i];

    const _Float16* bp = Wt + (size_t)(lane & 15) * 512 + (lane >> 4) * 8;

    h8 bfA[16], bfB[16];
    auto bload = [&](h8* d, int nt) {
        const _Float16* bn = bp + (size_t)nt * (16 * 512);
#pragma unroll
        for (int ks = 0; ks < 16; ++ks) d[ks] = *(const h8*)(bn + ks * 32);
    };
    auto mmaepi = [&](const h8* bf, int nt) {
        f4 c0 = (f4){0.f, 0.f, 0.f, 0.f}, c1 = c0, c2 = c0, c3 = c0;
#pragma unroll
        for (int q = 0; q < 4; ++q) {    // 4 independent K-chains, 4 deep
            c0 = __builtin_amdgcn_mfma_f32_16x16x32_f16(a[q],      bf[q],      c0, 0, 0, 0);
            c1 = __builtin_amdgcn_mfma_f32_16x16x32_f16(a[4 + q],  bf[4 + q],  c1, 0, 0, 0);
            c2 = __builtin_amdgcn_mfma_f32_16x16x32_f16(a[8 + q],  bf[8 + q],  c2, 0, 0, 0);
            c3 = __builtin_amdgcn_mfma_f32_16x16x32_f16(a[12 + q], bf[12 + q], c3, 0, 0, 0);
        }
        f4 c = (c0 + c1) + (c2 + c3);
        int col = nt * 16 + (lane & 15);
        float bcol = bias[col];
#pragma unroll
        for (int i = 0; i < 4; ++i) {
            int gr = base + r0 + i;
            float v = c[i] * rn[i] + bcol;
            if (mode == 0) {
                v = (v > 0.f) ? v : (__expf(v) - 1.0f);   // ELU, ~1e-8 vs expm1
                uint32_t j = (uint32_t)(gr * 512 + col);
                uint32_t g = (mask[j >> 5] >> (j & 31)) & 1u;
                v = g ? (v * 1.25f) : 0.0f;
                AT[(r0 + i) * LDF + col] = (_Float16)v;
            } else {
                fout[(size_t)gr * 512 + col] = v;
            }
        }
    };

    bload(bfA, 0);
    for (int nt = 0; nt < 32; nt += 2) {
        bload(bfB, nt + 1);
        mmaepi(bfA, nt);
        if (nt + 2 < 32) bload(bfA, nt + 2);
        mmaepi(bfB, nt + 1);
    }

    // ---- phase 3: coalesced row stores (mode 0) ----
    if (mode == 0) {
        __syncthreads();
#pragma unroll
        for (int rr = 0; rr < 16; ++rr)
            *(h8*)&yout[(size_t)(base + rr) * 512 + lane * 8] =
                *(const h8*)&AT[rr * LDF + lane * 8];
    }
}

// ---------------- launch ----------------
extern "C" void kernel_launch(void* const* d_in, const int* in_sizes, int n_in,
                              void* d_out, int out_size, void* d_ws, size_t ws_size,
                              hipStream_t stream) {
    const float* h   = (const float*)d_in[0];
    const int*   src = (const int*)d_in[1];
    const int*   dst = (const int*)d_in[2];
    const float* ew  = (const float*)d_in[3];
    const float* W0  = (const float*)d_in[4];
    const float* b0  = (const float*)d_in[5];
    const float* W1  = (const float*)d_in[6];
    const float* b1  = (const float*)d_in[7];
    const float* W2  = (const float*)d_in[8];
    const float* b2  = (const float*)d_in[9];
    float* out = (float*)d_out;

    char* ws = (char*)d_ws;
    _Float16* y16  = (_Float16*)ws; ws += (size_t)TOT * 2;            // 10.24 MB
    _Float16* y16b = (_Float16*)ws; ws += (size_t)TOT * 2;            // 10.24 MB
    _Float16* Wt   = (_Float16*)ws; ws += (size_t)3 * 512 * 512 * 2;  // 1.57 MB
    // the next three must stay contiguous: zeroed with ONE memset
    int* degi_in  = (int*)ws;  ws += N_NODES * 4;
    int* degi_out = (int*)ws;  ws += N_NODES * 4;
    int* cursor   = (int*)ws;  ws += N_NODES * 4;
    int* row_ptr  = (int*)ws;  ws += (N_NODES + 1) * 4;
    ws = (char*)(((uintptr_t)ws + 15) & ~(uintptr_t)15);
    int2* csr     = (int2*)ws; ws += (size_t)N_EDGES * 8;
    float* rn_in  = (float*)ws; ws += N_NODES * 4;
    float* rn_out = (float*)ws; ws += N_NODES * 4;
    uint32_t* mask1 = (uint32_t*)ws; ws += (size_t)NMASK * 4;         // 640 KB
    uint32_t* mask2 = (uint32_t*)ws; ws += (size_t)NMASK * 4;         // 640 KB

    hipMemsetAsync(degi_in, 0, 3 * N_NODES * 4, stream);

    // partitionable split: subkey i = both lanes of cipher(key=(0,42), x0=0, x1=i)
    uint32_t dk[3][2];
    for (int i = 0; i < 3; ++i) {
        uint32_t c0 = 0u, c1 = (uint32_t)i;
        tf2x32(0u, 42u, c0, c1);
        dk[i][0] = c0; dk[i][1] = c1;
    }

    pre_kernel<<<PRE_BLKS, 256, 0, stream>>>(src, dst, degi_out, degi_in,
                                             W0, W1, W2, Wt, h, y16,
                                             dk[0][0], dk[0][1],
                                             dk[1][0], dk[1][1], mask1,
                                             dk[2][0], dk[2][1], mask2);
    scan_kernel<<<1, 1024, 0, stream>>>(degi_in, degi_out, row_ptr, rn_in, rn_out);
    fill_kernel<<<(N_EDGES + 255) / 256, 256, 0, stream>>>(src, dst, ew, row_ptr,
                                                           rn_out, cursor, csr);

    // layer 0: y16 -> y16b ; layer 1: y16b -> y16 ; layer 2: y16 -> out (f32)
    fused_kernel<<<625, 64, 0, stream>>>(y16, row_ptr, csr, Wt,
                                         b0, rn_in, mask1, y16b, nullptr, 0);
    fused_kernel<<<625, 64, 0, stream>>>(y16b, row_ptr, csr, Wt + (size_t)512 * 512,
                                         b1, rn_in, mask2, y16, nullptr, 0);
    fused_kernel<<<625, 64, 0, stream>>>(y16, row_ptr, csr, Wt + (size_t)2 * 512 * 512,
                                         b2, rn_in, nullptr, nullptr, out, 1);
}

// Round 6
// 378.185 us; speedup vs baseline: 1.1882x; 1.1882x over previous
//
#include <hip/hip_runtime.h>
#include <stdint.h>

#define N_NODES 10000
#define N_EDGES 160000
#define D 512
#define TOT (N_NODES * D)          // 5,120,000
#define NMASK (TOT / 32)           // 160,000 u32 words per dropout mask
#define CAP 64                     // ELL slots/node; P(Poisson(16) > 64) ~ 1e-18
#define LDF 520                    // fp16 row stride for the 16x512 LDS slab

typedef _Float16 h8 __attribute__((ext_vector_type(8)));
typedef float f4 __attribute__((ext_vector_type(4)));

// ---------------- threefry2x32 (JAX partitionable semantics) ----------------
__host__ __device__ inline uint32_t rotl32(uint32_t v, int r) {
    return (v << r) | (v >> (32 - r));
}

__host__ __device__ inline void tf2x32(uint32_t k0, uint32_t k1,
                                       uint32_t& x0, uint32_t& x1) {
    uint32_t k2 = k0 ^ k1 ^ 0x1BD11BDAu;
    x0 += k0; x1 += k1;
    x0 += x1; x1 = rotl32(x1, 13); x1 ^= x0;
    x0 += x1; x1 = rotl32(x1, 15); x1 ^= x0;
    x0 += x1; x1 = rotl32(x1, 26); x1 ^= x0;
    x0 += x1; x1 = rotl32(x1,  6); x1 ^= x0;
    x0 += k1; x1 += k2 + 1u;
    x0 += x1; x1 = rotl32(x1, 17); x1 ^= x0;
    x0 += x1; x1 = rotl32(x1, 29); x1 ^= x0;
    x0 += x1; x1 = rotl32(x1, 16); x1 ^= x0;
    x0 += x1; x1 = rotl32(x1, 24); x1 ^= x0;
    x0 += k2; x1 += k0 + 2u;
    x0 += x1; x1 = rotl32(x1, 13); x1 ^= x0;
    x0 += x1; x1 = rotl32(x1, 15); x1 ^= x0;
    x0 += x1; x1 = rotl32(x1, 26); x1 ^= x0;
    x0 += x1; x1 = rotl32(x1,  6); x1 ^= x0;
    x0 += k0; x1 += k1 + 3u;
    x0 += x1; x1 = rotl32(x1, 17); x1 ^= x0;
    x0 += x1; x1 = rotl32(x1, 29); x1 ^= x0;
    x0 += x1; x1 = rotl32(x1, 16); x1 ^= x0;
    x0 += x1; x1 = rotl32(x1, 24); x1 ^= x0;
    x0 += k1; x1 += k2 + 4u;
    x0 += x1; x1 = rotl32(x1, 13); x1 ^= x0;
    x0 += x1; x1 = rotl32(x1, 15); x1 ^= x0;
    x0 += x1; x1 = rotl32(x1, 26); x1 ^= x0;
    x0 += x1; x1 = rotl32(x1,  6); x1 ^= x0;
    x0 += k2; x1 += k0 + 5u;
}

__device__ __forceinline__ uint32_t dropout_bit(uint32_t k0, uint32_t k1, uint32_t j) {
    uint32_t c0 = 0u, c1 = j;
    tf2x32(k0, k1, c0, c1);
    uint32_t bits = c0 ^ c1;
    float u = __uint_as_float((bits >> 9) | 0x3f800000u) - 1.0f;
    return (u < 0.8f) ? 1u : 0u;
}

// ---------------- pre-pass: hist(deg_out) + Wt + dropout0 + mask1 + mask2 ---
// block ranges: [0,625) hist, [625,817) wconvert, [817,5817) dropout layer 0,
// [5817,6442) mask1, [6442,7067) mask2.
#define HIST_BLKS 625
#define WCONV_BLKS 192
#define DROP_BLKS 5000
#define MASKG_BLKS 625             // NMASK / 256
#define PRE_BLKS (HIST_BLKS + WCONV_BLKS + DROP_BLKS + 2 * MASKG_BLKS)
__global__ __launch_bounds__(256)
void pre_kernel(const int* __restrict__ src, int* __restrict__ deg_out,
                const float* __restrict__ W0, const float* __restrict__ W1,
                const float* __restrict__ W2, _Float16* __restrict__ Wt,
                const float* __restrict__ x, _Float16* __restrict__ y,
                uint32_t k0, uint32_t k1,
                uint32_t m1k0, uint32_t m1k1, uint32_t* __restrict__ mask1,
                uint32_t m2k0, uint32_t m2k1, uint32_t* __restrict__ mask2) {
    __shared__ float tile[64][65];
    int b = blockIdx.x;
    int t = threadIdx.x;
    if (b < HIST_BLKS) {
        int e = b * 256 + t;                       // exactly covers N_EDGES
        atomicAdd(&deg_out[src[e]], 1);
    } else if (b < HIST_BLKS + WCONV_BLKS) {
        int b2 = b - HIST_BLKS;
        int bx = b2 & 7, by = (b2 >> 3) & 7, bz = b2 >> 6;
        const float* W = (bz == 0) ? W0 : (bz == 1) ? W1 : W2;
        _Float16* T = Wt + (size_t)bz * 512 * 512;
        int r0 = by * 64, c0 = bx * 64;
        int c = t & 63, rq = t >> 6;
#pragma unroll
        for (int i = 0; i < 16; ++i) {
            int r = rq + i * 4;
            tile[r][c] = W[(size_t)(r0 + r) * 512 + c0 + c];
        }
        __syncthreads();
        int k = t & 63, nq = t >> 6;
#pragma unroll
        for (int i = 0; i < 16; ++i) {
            int n = nq + i * 4;
            T[(size_t)(c0 + n) * 512 + r0 + k] = (_Float16)tile[k][n];
        }
    } else if (b < HIST_BLKS + WCONV_BLKS + DROP_BLKS) {
        int b3 = b - HIST_BLKS - WCONV_BLKS;
        int j = (b3 * 256 + t) * 4;
        if (j >= TOT) return;
        float4 xv = *(const float4*)&x[j];
        _Float16 r[4];
        uint32_t jj = (uint32_t)j;
#pragma unroll
        for (int i = 0; i < 4; ++i) {
            float g = dropout_bit(k0, k1, jj + (uint32_t)i) ? 1.0f : 0.0f;
            float xi = (&xv.x)[i];
            r[i] = (_Float16)(g * (xi * 1.25f));
        }
        *(ushort4*)&y[j] = *(ushort4*)r;
    } else {
        int b4 = b - HIST_BLKS - WCONV_BLKS - DROP_BLKS;
        int which = b4 / MASKG_BLKS;               // 0 -> mask1, 1 -> mask2
        int gtid = (b4 % MASKG_BLKS) * 256 + t;    // 0..159999 exactly
        uint32_t mk0 = which ? m2k0 : m1k0;
        uint32_t mk1 = which ? m2k1 : m1k1;
        uint32_t* m = which ? mask2 : mask1;
        uint32_t w = 0, jb = (uint32_t)gtid * 32u;
#pragma unroll 4
        for (int i = 0; i < 32; ++i)
            w |= dropout_bit(mk0, mk1, jb + (uint32_t)i) << i;
        m[gtid] = w;
    }
}

// ---------------- ELL fill: no scan needed ----------------------------------
// Slot assignment via atomicAdd on cnt_in (which doubles as in-degree for
// rn_in later). Edge weight pre-multiplied by rn_out[src] computed inline
// from deg_out (identical expression/bits as the old scan's rn_out).
__global__ __launch_bounds__(256)
void fill_kernel(const int* __restrict__ src, const int* __restrict__ dst,
                 const float* __restrict__ ew, const int* __restrict__ deg_out,
                 int* __restrict__ cnt_in, int2* __restrict__ ell) {
    int e = blockIdx.x * 256 + threadIdx.x;        // grid exactly covers N_EDGES
    int v = dst[e];
    int sn = src[e];
    int pos = atomicAdd(&cnt_in[v], 1);
    float rno = 1.0f / sqrtf(fmaxf((float)deg_out[sn], 1.0f));
    if (pos < CAP)
        ell[(size_t)v * CAP + pos] = make_int2(sn, __float_as_int(ew[e] * rno));
}

// ---------------- fused layer: aggregate + GEMM + epilogue ------------------
// 625 blocks x 4 waves; block owns 16-node m-tile. Wave w gathers nodes
// 4w..4w+3 into a 16x520 LDS slab (16/4/1-deep edge unroll, 16B/lane loads),
// then computes the 16 x [w*128, (w+1)*128) output strip: A-frags from LDS
// (64 VGPR), B streamed from L2-resident Wt into double-buffered register
// fragments, 16 MFMA per 16x16 n-tile in 4 independent K-chains, epilogue
// (rn_in + bias + ELU + mask-bit dropout) immediate, coalesced row stores.
__global__ __launch_bounds__(256)
void fused_layer(const _Float16* __restrict__ yin, const int* __restrict__ cnt_in,
                 const int2* __restrict__ ell, const _Float16* __restrict__ Wt,
                 const float* __restrict__ bias, const uint32_t* __restrict__ mask,
                 _Float16* __restrict__ yout, float* __restrict__ fout, int mode) {
    __shared__ _Float16 AT[16 * LDF];   // 16.6 KB
    const int tid = threadIdx.x;
    const int w = tid >> 6, lane = tid & 63;
    const int base = blockIdx.x * 16;
    const _Float16* yl = yin + lane * 8;

    // ---- gather: 4 nodes per wave ----
    for (int i = 0; i < 4; ++i) {
        int row = w * 4 + i;
        int node = base + row;
        int deg = cnt_in[node];
        if (deg > CAP) deg = CAP;
        const int2* ep = ell + (size_t)node * CAP;
        float acc[8] = {0, 0, 0, 0, 0, 0, 0, 0};
        int k = 0;
        for (; k + 15 < deg; k += 16) {
            int2 e[16];
#pragma unroll
            for (int u = 0; u < 16; ++u) e[u] = ep[k + u];
            h8 v[16];
#pragma unroll
            for (int u = 0; u < 16; ++u) v[u] = *(const h8*)&yl[(size_t)e[u].x * 512];
#pragma unroll
            for (int u = 0; u < 16; ++u) {
                float wt = __int_as_float(e[u].y);
#pragma unroll
                for (int j = 0; j < 8; ++j) acc[j] += wt * (float)v[u][j];
            }
        }
        for (; k + 3 < deg; k += 4) {
            int2 e[4];
#pragma unroll
            for (int u = 0; u < 4; ++u) e[u] = ep[k + u];
            h8 v[4];
#pragma unroll
            for (int u = 0; u < 4; ++u) v[u] = *(const h8*)&yl[(size_t)e[u].x * 512];
#pragma unroll
            for (int u = 0; u < 4; ++u) {
                float wt = __int_as_float(e[u].y);
#pragma unroll
                for (int j = 0; j < 8; ++j) acc[j] += wt * (float)v[u][j];
            }
        }
        for (; k < deg; ++k) {
            int2 e0 = ep[k];
            float wt = __int_as_float(e0.y);
            h8 v = *(const h8*)&yl[(size_t)e0.x * 512];
#pragma unroll
            for (int j = 0; j < 8; ++j) acc[j] += wt * (float)v[j];
        }
        _Float16 r[8];
#pragma unroll
        for (int j = 0; j < 8; ++j) r[j] = (_Float16)acc[j];
        *(h8*)&AT[row * LDF + lane * 8] = *(h8*)r;
    }
    __syncthreads();

    // ---- A-frags to registers ----
    h8 a[16];
#pragma unroll
    for (int ks = 0; ks < 16; ++ks)
        a[ks] = *(const h8*)&AT[(lane & 15) * LDF + ks * 32 + (lane >> 4) * 8];
    __syncthreads();                 // AT now reusable as output staging

    const int r0 = (lane >> 4) * 4;
    float rn[4];
#pragma unroll
    for (int i = 0; i < 4; ++i) {
        int d = cnt_in[base + r0 + i];
        rn[i] = 1.0f / sqrtf(fmaxf((float)d, 1.0f));
    }

    const _Float16* bp = Wt + (size_t)(lane & 15) * 512 + (lane >> 4) * 8;

    h8 bfA[16], bfB[16];
    auto bload = [&](h8* d, int nt) {
        const _Float16* bn = bp + (size_t)nt * (16 * 512);
#pragma unroll
        for (int ks = 0; ks < 16; ++ks) d[ks] = *(const h8*)(bn + ks * 32);
    };
    auto mmaepi = [&](const h8* bf, int nt) {
        f4 c0 = (f4){0.f, 0.f, 0.f, 0.f}, c1 = c0, c2 = c0, c3 = c0;
#pragma unroll
        for (int q = 0; q < 4; ++q) {    // 4 independent K-chains, 4 deep
            c0 = __builtin_amdgcn_mfma_f32_16x16x32_f16(a[q],      bf[q],      c0, 0, 0, 0);
            c1 = __builtin_amdgcn_mfma_f32_16x16x32_f16(a[4 + q],  bf[4 + q],  c1, 0, 0, 0);
            c2 = __builtin_amdgcn_mfma_f32_16x16x32_f16(a[8 + q],  bf[8 + q],  c2, 0, 0, 0);
            c3 = __builtin_amdgcn_mfma_f32_16x16x32_f16(a[12 + q], bf[12 + q], c3, 0, 0, 0);
        }
        f4 c = (c0 + c1) + (c2 + c3);
        int col = nt * 16 + (lane & 15);
        float bcol = bias[col];
#pragma unroll
        for (int i = 0; i < 4; ++i) {
            int gr = base + r0 + i;
            float v = c[i] * rn[i] + bcol;
            if (mode == 0) {
                v = (v > 0.f) ? v : (__expf(v) - 1.0f);   // ELU, ~1e-8 vs expm1
                uint32_t j = (uint32_t)(gr * 512 + col);
                uint32_t g = (mask[j >> 5] >> (j & 31)) & 1u;
                v = g ? (v * 1.25f) : 0.0f;
                AT[(r0 + i) * LDF + col] = (_Float16)v;
            } else {
                fout[(size_t)gr * 512 + col] = v;
            }
        }
    };

    const int nt0 = w * 8;               // this wave's 8 n-tiles (128 cols)
    bload(bfA, nt0);
#pragma unroll 1
    for (int j = 0; j < 8; j += 2) {
        bload(bfB, nt0 + j + 1);
        mmaepi(bfA, nt0 + j);
        if (j + 2 < 8) bload(bfA, nt0 + j + 2);
        mmaepi(bfB, nt0 + j + 1);
    }

    // ---- coalesced row stores (mode 0) ----
    if (mode == 0) {
        __syncthreads();
#pragma unroll
        for (int i = 0; i < 4; ++i) {
            int c = tid + 256 * i;       // 1024 chunks = 16 rows x 64 h8
            int row = c >> 6, col8 = c & 63;
            *(h8*)&yout[(size_t)(base + row) * 512 + col8 * 8] =
                *(const h8*)&AT[row * LDF + col8 * 8];
        }
    }
}

// ---------------- launch: 6 GPU ops total -----------------------------------
extern "C" void kernel_launch(void* const* d_in, const int* in_sizes, int n_in,
                              void* d_out, int out_size, void* d_ws, size_t ws_size,
                              hipStream_t stream) {
    const float* x   = (const float*)d_in[0];
    const int*   src = (const int*)d_in[1];
    const int*   dst = (const int*)d_in[2];
    const float* ew  = (const float*)d_in[3];
    const float* W0  = (const float*)d_in[4];
    const float* b0  = (const float*)d_in[5];
    const float* W1  = (const float*)d_in[6];
    const float* b1  = (const float*)d_in[7];
    const float* W2  = (const float*)d_in[8];
    const float* b2  = (const float*)d_in[9];
    float* out = (float*)d_out;

    char* ws = (char*)d_ws;
    _Float16* y16  = (_Float16*)ws; ws += (size_t)TOT * 2;            // 10.24 MB
    _Float16* y16b = (_Float16*)ws; ws += (size_t)TOT * 2;            // 10.24 MB
    _Float16* Wt   = (_Float16*)ws; ws += (size_t)3 * 512 * 512 * 2;  // 1.57 MB
    // deg_out + cnt_in contiguous: zeroed with ONE memset
    int* deg_out = (int*)ws;   ws += N_NODES * 4;
    int* cnt_in  = (int*)ws;   ws += N_NODES * 4;
    ws = (char*)(((uintptr_t)ws + 15) & ~(uintptr_t)15);
    int2* ell    = (int2*)ws;  ws += (size_t)N_NODES * CAP * 8;       // 5.12 MB
    uint32_t* mask1 = (uint32_t*)ws; ws += (size_t)NMASK * 4;         // 640 KB
    uint32_t* mask2 = (uint32_t*)ws; ws += (size_t)NMASK * 4;         // 640 KB

    // partitionable split: subkey i = both lanes of cipher(key=(0,42), x0=0, x1=i)
    uint32_t dk[3][2];
    for (int i = 0; i < 3; ++i) {
        uint32_t c0 = 0u, c1 = (uint32_t)i;
        tf2x32(0u, 42u, c0, c1);
        dk[i][0] = c0; dk[i][1] = c1;
    }

    hipMemsetAsync(deg_out, 0, 2 * N_NODES * 4, stream);

    pre_kernel<<<PRE_BLKS, 256, 0, stream>>>(src, deg_out, W0, W1, W2, Wt,
                                             x, y16, dk[0][0], dk[0][1],
                                             dk[1][0], dk[1][1], mask1,
                                             dk[2][0], dk[2][1], mask2);
    fill_kernel<<<N_EDGES / 256, 256, 0, stream>>>(src, dst, ew, deg_out,
                                                   cnt_in, ell);

    // layer 0: y16 -> y16b ; layer 1: y16b -> y16 ; layer 2: y16 -> out (f32)
    fused_layer<<<625, 256, 0, stream>>>(y16, cnt_in, ell, Wt,
                                         b0, mask1, y16b, nullptr, 0);
    fused_layer<<<625, 256, 0, stream>>>(y16b, cnt_in, ell, Wt + (size_t)512 * 512,
                                         b1, mask2, y16, nullptr, 0);
    fused_layer<<<625, 256, 0, stream>>>(y16, cnt_in, ell, Wt + (size_t)2 * 512 * 512,
                                         b2, nullptr, nullptr, out, 1);
}

// Round 7
// 325.294 us; speedup vs baseline: 1.3814x; 1.1626x over previous
//
#include <hip/hip_runtime.h>
#include <stdint.h>

#define N_NODES 10000
#define N_EDGES 160000
#define D 512
#define TOT (N_NODES * D)          // 5,120,000
#define NMASK (TOT / 32)           // 160,000 u32 words per dropout mask
#define CAP 64                     // ELL slots/node; P(Poisson(16) > 64) ~ 1e-18
#define MT 32                      // nodes per fused block
#define NBLK_F 313                 // ceil(10000/32)
#define LDA3 520                   // A-slab row stride (halves)
#define LDB 40                     // B-slab row stride (32 + 8 pad halves)

typedef _Float16 h8 __attribute__((ext_vector_type(8)));
typedef float f4 __attribute__((ext_vector_type(4)));

// ---------------- threefry2x32 (JAX partitionable semantics) ----------------
__host__ __device__ inline uint32_t rotl32(uint32_t v, int r) {
    return (v << r) | (v >> (32 - r));
}

__host__ __device__ inline void tf2x32(uint32_t k0, uint32_t k1,
                                       uint32_t& x0, uint32_t& x1) {
    uint32_t k2 = k0 ^ k1 ^ 0x1BD11BDAu;
    x0 += k0; x1 += k1;
    x0 += x1; x1 = rotl32(x1, 13); x1 ^= x0;
    x0 += x1; x1 = rotl32(x1, 15); x1 ^= x0;
    x0 += x1; x1 = rotl32(x1, 26); x1 ^= x0;
    x0 += x1; x1 = rotl32(x1,  6); x1 ^= x0;
    x0 += k1; x1 += k2 + 1u;
    x0 += x1; x1 = rotl32(x1, 17); x1 ^= x0;
    x0 += x1; x1 = rotl32(x1, 29); x1 ^= x0;
    x0 += x1; x1 = rotl32(x1, 16); x1 ^= x0;
    x0 += x1; x1 = rotl32(x1, 24); x1 ^= x0;
    x0 += k2; x1 += k0 + 2u;
    x0 += x1; x1 = rotl32(x1, 13); x1 ^= x0;
    x0 += x1; x1 = rotl32(x1, 15); x1 ^= x0;
    x0 += x1; x1 = rotl32(x1, 26); x1 ^= x0;
    x0 += x1; x1 = rotl32(x1,  6); x1 ^= x0;
    x0 += k0; x1 += k1 + 3u;
    x0 += x1; x1 = rotl32(x1, 17); x1 ^= x0;
    x0 += x1; x1 = rotl32(x1, 29); x1 ^= x0;
    x0 += x1; x1 = rotl32(x1, 16); x1 ^= x0;
    x0 += x1; x1 = rotl32(x1, 24); x1 ^= x0;
    x0 += k1; x1 += k2 + 4u;
    x0 += x1; x1 = rotl32(x1, 13); x1 ^= x0;
    x0 += x1; x1 = rotl32(x1, 15); x1 ^= x0;
    x0 += x1; x1 = rotl32(x1, 26); x1 ^= x0;
    x0 += x1; x1 = rotl32(x1,  6); x1 ^= x0;
    x0 += k2; x1 += k0 + 5u;
}

__device__ __forceinline__ uint32_t dropout_bit(uint32_t k0, uint32_t k1, uint32_t j) {
    uint32_t c0 = 0u, c1 = j;
    tf2x32(k0, k1, c0, c1);
    uint32_t bits = c0 ^ c1;
    float u = __uint_as_float((bits >> 9) | 0x3f800000u) - 1.0f;
    return (u < 0.8f) ? 1u : 0u;
}

// ---------------- pre-pass: hist(deg_out) + Wt + dropout0 + mask1 + mask2 ---
#define HIST_BLKS 625
#define WCONV_BLKS 192
#define DROP_BLKS 5000
#define MASKG_BLKS 625             // NMASK / 256
#define PRE_BLKS (HIST_BLKS + WCONV_BLKS + DROP_BLKS + 2 * MASKG_BLKS)
__global__ __launch_bounds__(256)
void pre_kernel(const int* __restrict__ src, int* __restrict__ deg_out,
                const float* __restrict__ W0, const float* __restrict__ W1,
                const float* __restrict__ W2, _Float16* __restrict__ Wt,
                const float* __restrict__ x, _Float16* __restrict__ y,
                uint32_t k0, uint32_t k1,
                uint32_t m1k0, uint32_t m1k1, uint32_t* __restrict__ mask1,
                uint32_t m2k0, uint32_t m2k1, uint32_t* __restrict__ mask2) {
    __shared__ float tile[64][65];
    int b = blockIdx.x;
    int t = threadIdx.x;
    if (b < HIST_BLKS) {
        int e = b * 256 + t;                       // exactly covers N_EDGES
        atomicAdd(&deg_out[src[e]], 1);
    } else if (b < HIST_BLKS + WCONV_BLKS) {
        int b2 = b - HIST_BLKS;
        int bx = b2 & 7, by = (b2 >> 3) & 7, bz = b2 >> 6;
        const float* W = (bz == 0) ? W0 : (bz == 1) ? W1 : W2;
        _Float16* T = Wt + (size_t)bz * 512 * 512;
        int r0 = by * 64, c0 = bx * 64;
        int c = t & 63, rq = t >> 6;
#pragma unroll
        for (int i = 0; i < 16; ++i) {
            int r = rq + i * 4;
            tile[r][c] = W[(size_t)(r0 + r) * 512 + c0 + c];
        }
        __syncthreads();
        int k = t & 63, nq = t >> 6;
#pragma unroll
        for (int i = 0; i < 16; ++i) {
            int n = nq + i * 4;
            T[(size_t)(c0 + n) * 512 + r0 + k] = (_Float16)tile[k][n];
        }
    } else if (b < HIST_BLKS + WCONV_BLKS + DROP_BLKS) {
        int b3 = b - HIST_BLKS - WCONV_BLKS;
        int j = (b3 * 256 + t) * 4;
        if (j >= TOT) return;
        float4 xv = *(const float4*)&x[j];
        _Float16 r[4];
        uint32_t jj = (uint32_t)j;
#pragma unroll
        for (int i = 0; i < 4; ++i) {
            float g = dropout_bit(k0, k1, jj + (uint32_t)i) ? 1.0f : 0.0f;
            float xi = (&xv.x)[i];
            r[i] = (_Float16)(g * (xi * 1.25f));
        }
        *(ushort4*)&y[j] = *(ushort4*)r;
    } else {
        int b4 = b - HIST_BLKS - WCONV_BLKS - DROP_BLKS;
        int which = b4 / MASKG_BLKS;               // 0 -> mask1, 1 -> mask2
        int gtid = (b4 % MASKG_BLKS) * 256 + t;    // 0..159999 exactly
        uint32_t mk0 = which ? m2k0 : m1k0;
        uint32_t mk1 = which ? m2k1 : m1k1;
        uint32_t* m = which ? mask2 : mask1;
        uint32_t w = 0, jb = (uint32_t)gtid * 32u;
#pragma unroll 4
        for (int i = 0; i < 32; ++i)
            w |= dropout_bit(mk0, mk1, jb + (uint32_t)i) << i;
        m[gtid] = w;
    }
}

// ---------------- ELL fill: no scan needed ----------------------------------
__global__ __launch_bounds__(256)
void fill_kernel(const int* __restrict__ src, const int* __restrict__ dst,
                 const float* __restrict__ ew, const int* __restrict__ deg_out,
                 int* __restrict__ cnt_in, int2* __restrict__ ell) {
    int e = blockIdx.x * 256 + threadIdx.x;        // grid exactly covers N_EDGES
    int v = dst[e];
    int sn = src[e];
    int pos = atomicAdd(&cnt_in[v], 1);
    float rno = 1.0f / sqrtf(fmaxf((float)deg_out[sn], 1.0f));
    if (pos < CAP)
        ell[(size_t)v * CAP + pos] = make_int2(sn, __float_as_int(ew[e] * rno));
}

// ---------------- fused layer v2: gather + LDS-tiled GEMM + epilogue --------
// 313 blocks x 512 thr (8 waves), m-tile = 32 nodes.
// Gather: wave w -> nodes w*4..w*4+3 (identical per-wave code to r6; 2504
//         gather waves total), rows written to AT[32][520] fp16 slab.
// GEMM:   classic LDS-tiled loop. Bs[512 cols][32K + 8 pad] staged
//         cooperatively each K-step (thread t reads 64B of Wt row t,
//         register-prefetched one step ahead -> global latency hidden under
//         MFMA). Waves split 2m x 4n: each wave 16 rows x 128 cols,
//         8 MFMA/K-step from LDS. B global traffic 160MB/layer streaming
//         (was 320MB scattered per-wave in r6 -> the measured 5.9TB/s L2 wall).
// LDS 33.3 + 41 = 74.3KB -> 2 blocks/CU: one block's GEMM overlaps the
// other's gather.
__global__ __launch_bounds__(512, 4)
void fused_layer(const _Float16* __restrict__ yin, const int* __restrict__ cnt_in,
                 const int2* __restrict__ ell, const _Float16* __restrict__ Wt,
                 const float* __restrict__ bias, const uint32_t* __restrict__ mask,
                 _Float16* __restrict__ yout, float* __restrict__ fout, int mode) {
    __shared__ _Float16 AT[MT * LDA3];   // 33.3 KB
    __shared__ _Float16 Bs[512 * LDB];   // 41.0 KB
    const int tid = threadIdx.x;
    const int w = tid >> 6, lane = tid & 63;
    const int base = blockIdx.x * MT;
    const _Float16* yl = yin + lane * 8;

    // ---- gather: 4 nodes per wave (8 waves -> 32 rows) ----
    for (int i = 0; i < 4; ++i) {
        int row = w * 4 + i;
        int node = base + row;
        int deg = (node < N_NODES) ? cnt_in[node] : 0;
        if (deg > CAP) deg = CAP;
        const int2* ep = ell + (size_t)node * CAP;
        float acc[8] = {0, 0, 0, 0, 0, 0, 0, 0};
        int k = 0;
        for (; k + 15 < deg; k += 16) {
            int2 e[16];
#pragma unroll
            for (int u = 0; u < 16; ++u) e[u] = ep[k + u];
            h8 v[16];
#pragma unroll
            for (int u = 0; u < 16; ++u) v[u] = *(const h8*)&yl[(size_t)e[u].x * 512];
#pragma unroll
            for (int u = 0; u < 16; ++u) {
                float wt = __int_as_float(e[u].y);
#pragma unroll
                for (int j = 0; j < 8; ++j) acc[j] += wt * (float)v[u][j];
            }
        }
        for (; k + 3 < deg; k += 4) {
            int2 e[4];
#pragma unroll
            for (int u = 0; u < 4; ++u) e[u] = ep[k + u];
            h8 v[4];
#pragma unroll
            for (int u = 0; u < 4; ++u) v[u] = *(const h8*)&yl[(size_t)e[u].x * 512];
#pragma unroll
            for (int u = 0; u < 4; ++u) {
                float wt = __int_as_float(e[u].y);
#pragma unroll
                for (int j = 0; j < 8; ++j) acc[j] += wt * (float)v[u][j];
            }
        }
        for (; k < deg; ++k) {
            int2 e0 = ep[k];
            float wt = __int_as_float(e0.y);
            h8 v = *(const h8*)&yl[(size_t)e0.x * 512];
#pragma unroll
            for (int j = 0; j < 8; ++j) acc[j] += wt * (float)v[j];
        }
        _Float16 r[8];
#pragma unroll
        for (int j = 0; j < 8; ++j) r[j] = (_Float16)acc[j];
        *(h8*)&AT[row * LDA3 + lane * 8] = *(h8*)r;
    }
    __syncthreads();

    // ---- GEMM: waves 2m x 4n, B staged per K-step (BK=32) ----
    const int mq = w & 1, nq = w >> 1;
    f4 acc[8];
#pragma unroll
    for (int i = 0; i < 8; ++i) acc[i] = (f4){0.f, 0.f, 0.f, 0.f};

    const _Float16* wrow = Wt + (size_t)tid * 512;    // thread t stages Wt row t
    _Float16* bw = &Bs[tid * LDB];
    const _Float16* arow = &AT[(mq * 16 + (lane & 15)) * LDA3 + (lane >> 4) * 8];
    const _Float16* brow = &Bs[(nq * 128 + (lane & 15)) * LDB + (lane >> 4) * 8];

    h8 rb0 = *(const h8*)(wrow + 0);
    h8 rb1 = *(const h8*)(wrow + 8);
    h8 rb2 = *(const h8*)(wrow + 16);
    h8 rb3 = *(const h8*)(wrow + 24);

    for (int ks = 0; ks < 16; ++ks) {
        *(h8*)(bw + 0)  = rb0;
        *(h8*)(bw + 8)  = rb1;
        *(h8*)(bw + 16) = rb2;
        *(h8*)(bw + 24) = rb3;
        __syncthreads();
        if (ks < 15) {                    // register prefetch next K-step
            const _Float16* nx = wrow + (ks + 1) * 32;
            rb0 = *(const h8*)(nx + 0);
            rb1 = *(const h8*)(nx + 8);
            rb2 = *(const h8*)(nx + 16);
            rb3 = *(const h8*)(nx + 24);
        }
        h8 a = *(const h8*)(arow + ks * 32);
#pragma unroll
        for (int nt = 0; nt < 8; ++nt) {
            h8 bf = *(const h8*)(brow + nt * 16 * LDB);
            acc[nt] = __builtin_amdgcn_mfma_f32_16x16x32_f16(a, bf, acc[nt], 0, 0, 0);
        }
        __syncthreads();
    }

    // ---- epilogue. C/D layout: col = lane&15, row = (lane>>4)*4 + reg ----
    const int r0g = (lane >> 4) * 4;
    float rn[4];
#pragma unroll
    for (int i = 0; i < 4; ++i) {
        int gr = base + mq * 16 + r0g + i;
        int d = (gr < N_NODES) ? cnt_in[gr] : 1;
        rn[i] = 1.0f / sqrtf(fmaxf((float)d, 1.0f));
    }
#pragma unroll
    for (int nt = 0; nt < 8; ++nt) {
        int col = nq * 128 + nt * 16 + (lane & 15);
        float bcol = bias[col];
#pragma unroll
        for (int i = 0; i < 4; ++i) {
            int gr = base + mq * 16 + r0g + i;
            if (gr >= N_NODES) continue;
            float v = acc[nt][i] * rn[i] + bcol;
            if (mode == 0) {
                v = (v > 0.f) ? v : (__expf(v) - 1.0f);   // ELU, ~1e-8 vs expm1
                uint32_t j = (uint32_t)(gr * 512 + col);
                uint32_t g = (mask[j >> 5] >> (j & 31)) & 1u;
                v = g ? (v * 1.25f) : 0.0f;
                AT[(mq * 16 + r0g + i) * LDA3 + col] = (_Float16)v;
            } else {
                fout[(size_t)gr * 512 + col] = v;
            }
        }
    }

    // ---- coalesced row stores (mode 0) ----
    if (mode == 0) {
        __syncthreads();
#pragma unroll
        for (int i = 0; i < 4; ++i) {
            int c = tid + 512 * i;       // 2048 chunks = 32 rows x 64 h8
            int row = c >> 6, col8 = c & 63;
            int gr = base + row;
            if (gr < N_NODES)
                *(h8*)&yout[(size_t)gr * 512 + col8 * 8] =
                    *(const h8*)&AT[row * LDA3 + col8 * 8];
        }
    }
}

// ---------------- launch: 6 GPU ops total -----------------------------------
extern "C" void kernel_launch(void* const* d_in, const int* in_sizes, int n_in,
                              void* d_out, int out_size, void* d_ws, size_t ws_size,
                              hipStream_t stream) {
    const float* x   = (const float*)d_in[0];
    const int*   src = (const int*)d_in[1];
    const int*   dst = (const int*)d_in[2];
    const float* ew  = (const float*)d_in[3];
    const float* W0  = (const float*)d_in[4];
    const float* b0  = (const float*)d_in[5];
    const float* W1  = (const float*)d_in[6];
    const float* b1  = (const float*)d_in[7];
    const float* W2  = (const float*)d_in[8];
    const float* b2  = (const float*)d_in[9];
    float* out = (float*)d_out;

    char* ws = (char*)d_ws;
    _Float16* y16  = (_Float16*)ws; ws += (size_t)TOT * 2;            // 10.24 MB
    _Float16* y16b = (_Float16*)ws; ws += (size_t)TOT * 2;            // 10.24 MB
    _Float16* Wt   = (_Float16*)ws; ws += (size_t)3 * 512 * 512 * 2;  // 1.57 MB
    // deg_out + cnt_in contiguous: zeroed with ONE memset
    int* deg_out = (int*)ws;   ws += N_NODES * 4;
    int* cnt_in  = (int*)ws;   ws += N_NODES * 4;
    ws = (char*)(((uintptr_t)ws + 15) & ~(uintptr_t)15);
    int2* ell    = (int2*)ws;  ws += (size_t)N_NODES * CAP * 8;       // 5.12 MB
    uint32_t* mask1 = (uint32_t*)ws; ws += (size_t)NMASK * 4;         // 640 KB
    uint32_t* mask2 = (uint32_t*)ws; ws += (size_t)NMASK * 4;         // 640 KB

    // partitionable split: subkey i = both lanes of cipher(key=(0,42), x0=0, x1=i)
    uint32_t dk[3][2];
    for (int i = 0; i < 3; ++i) {
        uint32_t c0 = 0u, c1 = (uint32_t)i;
        tf2x32(0u, 42u, c0, c1);
        dk[i][0] = c0; dk[i][1] = c1;
    }

    hipMemsetAsync(deg_out, 0, 2 * N_NODES * 4, stream);

    pre_kernel<<<PRE_BLKS, 256, 0, stream>>>(src, deg_out, W0, W1, W2, Wt,
                                             x, y16, dk[0][0], dk[0][1],
                                             dk[1][0], dk[1][1], mask1,
                                             dk[2][0], dk[2][1], mask2);
    fill_kernel<<<N_EDGES / 256, 256, 0, stream>>>(src, dst, ew, deg_out,
                                                   cnt_in, ell);

    // layer 0: y16 -> y16b ; layer 1: y16b -> y16 ; layer 2: y16 -> out (f32)
    fused_layer<<<NBLK_F, 512, 0, stream>>>(y16, cnt_in, ell, Wt,
                                            b0, mask1, y16b, nullptr, 0);
    fused_layer<<<NBLK_F, 512, 0, stream>>>(y16b, cnt_in, ell, Wt + (size_t)512 * 512,
                                            b1, mask2, y16, nullptr, 0);
    fused_layer<<<NBLK_F, 512, 0, stream>>>(y16, cnt_in, ell, Wt + (size_t)2 * 512 * 512,
                                            b2, nullptr, nullptr, out, 1);
}